// Round 1
// baseline (6229.715 us; speedup 1.0000x reference)
//
#include <hip/hip_runtime.h>

// LSTM T=512 B=128 I=H=512.  Persistent-kernel design:
//   grid = 128 WGs (4 row-groups x 32 col-groups), each WG owns a
//   [32 rows x 16 h-cols] slice of the state for the entire sequence.
//   Weights (fp16, gate-interleaved) live in VGPRs (128/lane). Waves split K:
//   wave w handles k in [256w, 256w+256) for all 64 gate cols; partial gates
//   reduced via LDS. c lives in registers. Grid barrier = device-scope
//   atomics + __threadfence (cross-XCD L2 wb/inv).

typedef _Float16 half_t;
typedef _Float16 half8 __attribute__((ext_vector_type(8)));
typedef float f32x4 __attribute__((ext_vector_type(4)));

#define NWG 128

// workspace layout (bytes)
#define WP_OFF   0u         // half [2048][1024]  gate-interleaved weights
#define BIAS_OFF 4194304u   // float [2048]       combined bias, interleaved
#define HBUF_OFF 4202496u   // half [2][128*512]  double-buffered h (fp16)
#define BAR_OFF  4464640u   // int [2]            arrive counter, release gen

__global__ void prep_kernel(const float* __restrict__ Wih,
                            const float* __restrict__ Whh,
                            const float* __restrict__ bih,
                            const float* __restrict__ bhh,
                            unsigned char* __restrict__ ws)
{
    half_t* Wp    = (half_t*)(ws + WP_OFF);
    float*  biasp = (float*)(ws + BIAS_OFF);
    int*    bar   = (int*)(ws + BAR_OFF);
    int bid = blockIdx.x, tid = threadIdx.x;
    if (bid < 1024) {
        // Wp[np][k], np = j*4+g  (j = h-col, g = gate i/f/g/o), K = [x | h]
        size_t e0 = ((size_t)bid * 256 + (size_t)tid) * 8;
        int np = (int)(e0 >> 10);
        int k  = (int)(e0 & 1023);
        int j = np >> 2, g = np & 3;
        int r = g * 512 + j;                      // row in original W_ih/W_hh
        const float* src = (k < 512) ? (Wih + (size_t)r * 512 + k)
                                     : (Whh + (size_t)r * 512 + (k - 512));
        float4 f0 = *(const float4*)(src);
        float4 f1 = *(const float4*)(src + 4);
        half8 h;
        h[0]=(half_t)f0.x; h[1]=(half_t)f0.y; h[2]=(half_t)f0.z; h[3]=(half_t)f0.w;
        h[4]=(half_t)f1.x; h[5]=(half_t)f1.y; h[6]=(half_t)f1.z; h[7]=(half_t)f1.w;
        *(half8*)(Wp + e0) = h;
    } else {
        for (int n = tid; n < 2048; n += 256) {
            int j = n >> 2, g = n & 3;
            int r = g * 512 + j;
            biasp[n] = bih[r] + bhh[r];
        }
        if (tid == 0) { bar[0] = 0; bar[1] = 0; }
    }
}

__device__ __forceinline__ void grid_barrier(int* bar, int gen) {
    __syncthreads();              // all waves' global writes complete (vmcnt)
    if (threadIdx.x == 0) {
        __threadfence();          // release: flush this XCD's L2 to coherence pt
        int old = __hip_atomic_fetch_add(&bar[0], 1, __ATOMIC_RELAXED,
                                         __HIP_MEMORY_SCOPE_AGENT);
        if (old == NWG * gen - 1) {
            __hip_atomic_store(&bar[1], gen, __ATOMIC_RELAXED,
                               __HIP_MEMORY_SCOPE_AGENT);
        } else {
            while (__hip_atomic_load(&bar[1], __ATOMIC_RELAXED,
                                     __HIP_MEMORY_SCOPE_AGENT) < gen)
                __builtin_amdgcn_s_sleep(1);
        }
        __threadfence();          // acquire: invalidate stale L1/L2 lines
    }
    __syncthreads();
}

__global__ __launch_bounds__(256, 1) void lstm_persistent(
    const float* __restrict__ x, float* __restrict__ out,
    unsigned char* __restrict__ ws)
{
    const half_t* Wp    = (const half_t*)(ws + WP_OFF);
    const float*  biasp = (const float*)(ws + BIAS_OFF);
    half_t*       hbuf  = (half_t*)(ws + HBUF_OFF);
    int*          bar   = (int*)(ws + BAR_OFF);

    const int tid  = threadIdx.x;
    const int wave = tid >> 6, lane = tid & 63;
    const int quad = lane >> 4, l16 = lane & 15;
    const int bid  = blockIdx.x;
    const int rowg = bid & 3, colg = bid >> 2;
    const int r0 = rowg * 32;     // batch rows [r0, r0+32)
    const int j0 = colg * 16;     // h-cols    [j0, j0+16)

    // ---- load stationary W fragments: wave's K-quarter x all 64 gate cols ----
    // lane holds W[np = 4*j0 + nb*16 + l16][k = wave*256 + kk*32 + quad*8 + 0..7]
    half8 wreg[8][4];
    {
        const half_t* wb = Wp + ((size_t)(4 * j0 + l16)) * 1024 + wave * 256 + quad * 8;
#pragma unroll
        for (int kk = 0; kk < 8; ++kk)
#pragma unroll
            for (int nb = 0; nb < 4; ++nb)
                wreg[kk][nb] = *(const half8*)(wb + (size_t)nb * 16 * 1024 + kk * 32);
    }

    // zero this WG's slice of h buffer 0
    for (int e = tid; e < 512; e += 256) {
        int b = e >> 4, j = e & 15;
        hbuf[(r0 + b) * 512 + j0 + j] = (half_t)0.f;
    }

    __shared__ float P[4][32][68];   // per-wave partial gates [wave][row][gatecol]

    float c0 = 0.f, c1 = 0.f;        // cell state, 2 cells/thread, registers

    grid_barrier(bar, 1);            // h0 zeros visible everywhere

    for (int t = 0; t < 512; ++t) {
        const half_t* hcur  = hbuf + (size_t)(t & 1) * 65536;
        half_t*       hnext = hbuf + (size_t)((t + 1) & 1) * 65536;

        f32x4 acc[2][4];
#pragma unroll
        for (int mb = 0; mb < 2; ++mb)
#pragma unroll
            for (int nb = 0; nb < 4; ++nb)
                acc[mb][nb] = (f32x4){0.f, 0.f, 0.f, 0.f};

        if (wave < 2) {
            // waves 0,1: A comes from x_t (fp32 -> fp16 on the fly)
            const float* xp0 = x + ((size_t)t * 128 + r0 + l16) * 512 + wave * 256 + quad * 8;
            const float* xp1 = xp0 + (size_t)16 * 512;
#pragma unroll
            for (int kk = 0; kk < 8; ++kk) {
                float4 f0 = *(const float4*)(xp0 + kk * 32);
                float4 f1 = *(const float4*)(xp0 + kk * 32 + 4);
                float4 f2 = *(const float4*)(xp1 + kk * 32);
                float4 f3 = *(const float4*)(xp1 + kk * 32 + 4);
                half8 a0, a1;
                a0[0]=(half_t)f0.x; a0[1]=(half_t)f0.y; a0[2]=(half_t)f0.z; a0[3]=(half_t)f0.w;
                a0[4]=(half_t)f1.x; a0[5]=(half_t)f1.y; a0[6]=(half_t)f1.z; a0[7]=(half_t)f1.w;
                a1[0]=(half_t)f2.x; a1[1]=(half_t)f2.y; a1[2]=(half_t)f2.z; a1[3]=(half_t)f2.w;
                a1[4]=(half_t)f3.x; a1[5]=(half_t)f3.y; a1[6]=(half_t)f3.z; a1[7]=(half_t)f3.w;
#pragma unroll
                for (int nb = 0; nb < 4; ++nb) {
                    acc[0][nb] = __builtin_amdgcn_mfma_f32_16x16x32_f16(a0, wreg[kk][nb], acc[0][nb], 0, 0, 0);
                    acc[1][nb] = __builtin_amdgcn_mfma_f32_16x16x32_f16(a1, wreg[kk][nb], acc[1][nb], 0, 0, 0);
                }
            }
        } else {
            // waves 2,3: A comes from h (fp16 double buffer)
            const half_t* hp0 = hcur + (size_t)(r0 + l16) * 512 + (wave - 2) * 256 + quad * 8;
            const half_t* hp1 = hp0 + (size_t)16 * 512;
#pragma unroll
            for (int kk = 0; kk < 8; ++kk) {
                half8 a0 = *(const half8*)(hp0 + kk * 32);
                half8 a1 = *(const half8*)(hp1 + kk * 32);
#pragma unroll
                for (int nb = 0; nb < 4; ++nb) {
                    acc[0][nb] = __builtin_amdgcn_mfma_f32_16x16x32_f16(a0, wreg[kk][nb], acc[0][nb], 0, 0, 0);
                    acc[1][nb] = __builtin_amdgcn_mfma_f32_16x16x32_f16(a1, wreg[kk][nb], acc[1][nb], 0, 0, 0);
                }
            }
        }

        // C/D layout: col = lane&15, row = quad*4 + reg  (m89-verified)
#pragma unroll
        for (int mb = 0; mb < 2; ++mb)
#pragma unroll
            for (int nb = 0; nb < 4; ++nb) {
                f32x4 v = acc[mb][nb];
#pragma unroll
                for (int r = 0; r < 4; ++r)
                    P[wave][mb * 16 + quad * 4 + r][nb * 16 + l16] = v[r];
            }
        __syncthreads();

        // reduce 4 wave-partials + bias, activations, state update
#pragma unroll
        for (int cc = 0; cc < 2; ++cc) {
            int cid = tid + cc * 256;
            int b = cid >> 4, jl = cid & 15;
            float4 s = {0.f, 0.f, 0.f, 0.f};
#pragma unroll
            for (int w = 0; w < 4; ++w) {
                float4 p = *(const float4*)&P[w][b][4 * jl];
                s.x += p.x; s.y += p.y; s.z += p.z; s.w += p.w;
            }
            float4 bi = *(const float4*)(biasp + 4 * (j0 + jl));
            float gi = s.x + bi.x, gf = s.y + bi.y, gz = s.z + bi.z, go = s.w + bi.w;
            float ig = 1.f / (1.f + __expf(-gi));
            float fg = 1.f / (1.f + __expf(-gf));
            float zg = 1.f - 2.f / (__expf(2.f * gz) + 1.f);   // tanh
            float og = 1.f / (1.f + __expf(-go));
            float cprev = cc ? c1 : c0;
            float cn = fg * cprev + ig * zg;
            if (cc) c1 = cn; else c0 = cn;
            float hn = og * (1.f - 2.f / (__expf(2.f * cn) + 1.f));
            int bg = r0 + b, jg = j0 + jl;
            out[(size_t)t * 65536 + (size_t)bg * 512 + jg] = hn;
            hnext[(size_t)bg * 512 + jg] = (half_t)hn;
            if (t == 511) {
                out[(size_t)33554432 + (size_t)bg * 512 + jg] = hn;          // hT
                out[(size_t)33554432 + 65536 + (size_t)bg * 512 + jg] = cn;  // cT
            }
        }

        grid_barrier(bar, t + 2);
    }
}

extern "C" void kernel_launch(void* const* d_in, const int* in_sizes, int n_in,
                              void* d_out, int out_size, void* d_ws, size_t ws_size,
                              hipStream_t stream)
{
    const float* x   = (const float*)d_in[0];
    // d_in[1] = time, unused by the base cell
    const float* Wih = (const float*)d_in[2];
    const float* Whh = (const float*)d_in[3];
    const float* bih = (const float*)d_in[4];
    const float* bhh = (const float*)d_in[5];
    unsigned char* ws = (unsigned char*)d_ws;
    float* out = (float*)d_out;

    prep_kernel<<<1025, 256, 0, stream>>>(Wih, Whh, bih, bhh, ws);
    lstm_persistent<<<NWG, 256, 0, stream>>>(x, out, ws);
}

// Round 2
// 4558.657 us; speedup vs baseline: 1.3666x; 1.3666x over previous
//
#include <hip/hip_runtime.h>

// LSTM T=512 B=128 I=H=512.  Persistent-kernel design:
//   grid = 128 WGs (4 row-groups x 32 col-groups), each WG owns a
//   [32 rows x 16 h-cols] slice of the state for the entire sequence.
//   Weights (fp16, gate-interleaved) live in VGPRs (128/lane). Waves split K:
//   wave w handles k in [256w, 256w+256) for all 64 gate cols; partial gates
//   reduced via LDS. c lives in registers.
//
// R2 change: NO __threadfence() in the grid barrier (agent fences emit
// buffer_wbl2/buffer_inv = full L2 writeback+invalidate, ~10us/step).
// Cross-XCD h traffic uses per-instruction coherent ops instead:
// __hip_atomic_{store,load}(RELAXED, AGENT) -> global_{store,load} sc0 sc1.
// __syncthreads() drains vmcnt(0) per wave before s_barrier, so all coherent
// h-stores are at the coherence point before the arrival atomicAdd.

typedef _Float16 half_t;
typedef _Float16 half8 __attribute__((ext_vector_type(8)));
typedef float f32x4 __attribute__((ext_vector_type(4)));
typedef unsigned long long u64;
typedef unsigned int u32;

#define NWG 128

// workspace layout (bytes)
#define WP_OFF   0u         // half [2048][1024]  gate-interleaved weights
#define BIAS_OFF 4194304u   // float [2048]       combined bias, interleaved
#define HBUF_OFF 4202496u   // half [2][128*512]  double-buffered h (fp16)
#define BAR_OFF  4464640u   // int [2]            arrive counter, release gen

__global__ void prep_kernel(const float* __restrict__ Wih,
                            const float* __restrict__ Whh,
                            const float* __restrict__ bih,
                            const float* __restrict__ bhh,
                            unsigned char* __restrict__ ws)
{
    half_t* Wp    = (half_t*)(ws + WP_OFF);
    float*  biasp = (float*)(ws + BIAS_OFF);
    int*    bar   = (int*)(ws + BAR_OFF);
    int bid = blockIdx.x, tid = threadIdx.x;
    if (bid < 1024) {
        // Wp[np][k], np = j*4+g  (j = h-col, g = gate i/f/g/o), K = [x | h]
        size_t e0 = ((size_t)bid * 256 + (size_t)tid) * 8;
        int np = (int)(e0 >> 10);
        int k  = (int)(e0 & 1023);
        int j = np >> 2, g = np & 3;
        int r = g * 512 + j;                      // row in original W_ih/W_hh
        const float* src = (k < 512) ? (Wih + (size_t)r * 512 + k)
                                     : (Whh + (size_t)r * 512 + (k - 512));
        float4 f0 = *(const float4*)(src);
        float4 f1 = *(const float4*)(src + 4);
        half8 h;
        h[0]=(half_t)f0.x; h[1]=(half_t)f0.y; h[2]=(half_t)f0.z; h[3]=(half_t)f0.w;
        h[4]=(half_t)f1.x; h[5]=(half_t)f1.y; h[6]=(half_t)f1.z; h[7]=(half_t)f1.w;
        *(half8*)(Wp + e0) = h;
    } else {
        for (int n = tid; n < 2048; n += 256) {
            int j = n >> 2, g = n & 3;
            int r = g * 512 + j;
            biasp[n] = bih[r] + bhh[r];
        }
        if (tid == 0) { bar[0] = 0; bar[1] = 0; }
    }
}

// coherent (agent-scope, L1/L2-bypassing) helpers — no cache maintenance
__device__ __forceinline__ half8 coh_load16(const half_t* p) {
    union { u64 q[2]; half8 h; } u;
    u.q[0] = __hip_atomic_load((const u64*)p,     __ATOMIC_RELAXED, __HIP_MEMORY_SCOPE_AGENT);
    u.q[1] = __hip_atomic_load((const u64*)p + 1, __ATOMIC_RELAXED, __HIP_MEMORY_SCOPE_AGENT);
    return u.h;
}
__device__ __forceinline__ void coh_store4(u32* p, u32 v) {
    __hip_atomic_store(p, v, __ATOMIC_RELAXED, __HIP_MEMORY_SCOPE_AGENT);
}

__device__ __forceinline__ void grid_barrier(int* bar, int gen) {
    __syncthreads();   // emits s_waitcnt vmcnt(0) per wave before s_barrier:
                       // all coherent h-stores are at the coherence point
    if (threadIdx.x == 0) {
        int old = __hip_atomic_fetch_add(&bar[0], 1, __ATOMIC_RELAXED,
                                         __HIP_MEMORY_SCOPE_AGENT);
        if (old == NWG * gen - 1) {
            __hip_atomic_store(&bar[1], gen, __ATOMIC_RELAXED,
                               __HIP_MEMORY_SCOPE_AGENT);
        } else {
            while (__hip_atomic_load(&bar[1], __ATOMIC_RELAXED,
                                     __HIP_MEMORY_SCOPE_AGENT) < gen)
                __builtin_amdgcn_s_sleep(1);
        }
    }
    __syncthreads();
}

__global__ __launch_bounds__(256, 1) void lstm_persistent(
    const float* __restrict__ x, float* __restrict__ out,
    unsigned char* __restrict__ ws)
{
    const half_t* Wp    = (const half_t*)(ws + WP_OFF);
    const float*  biasp = (const float*)(ws + BIAS_OFF);
    half_t*       hbuf  = (half_t*)(ws + HBUF_OFF);
    int*          bar   = (int*)(ws + BAR_OFF);

    const int tid  = threadIdx.x;
    const int wave = tid >> 6, lane = tid & 63;
    const int quad = lane >> 4, l16 = lane & 15;
    const int bid  = blockIdx.x;
    const int rowg = bid & 3, colg = bid >> 2;
    const int r0 = rowg * 32;     // batch rows [r0, r0+32)
    const int j0 = colg * 16;     // h-cols    [j0, j0+16)

    // ---- load stationary W fragments: wave's K-quarter x all 64 gate cols ----
    // lane holds W[np = 4*j0 + nb*16 + l16][k = wave*256 + kk*32 + quad*8 + 0..7]
    half8 wreg[8][4];
    {
        const half_t* wb = Wp + ((size_t)(4 * j0 + l16)) * 1024 + wave * 256 + quad * 8;
#pragma unroll
        for (int kk = 0; kk < 8; ++kk)
#pragma unroll
            for (int nb = 0; nb < 4; ++nb)
                wreg[kk][nb] = *(const half8*)(wb + (size_t)nb * 16 * 1024 + kk * 32);
    }

    // zero this WG's slice of h buffer 0 (coherent stores: readers bypass L2)
    {
        int b = tid >> 3, jp = tid & 7;
        coh_store4((u32*)(hbuf + (size_t)(r0 + b) * 512 + j0 + 2 * jp), 0u);
    }

    __shared__ float P[4][32][68];   // per-wave partial gates [wave][row][gatecol]

    float c0 = 0.f, c1 = 0.f;        // cell state: cells (b,2jp),(b,2jp+1)

    grid_barrier(bar, 1);            // h0 zeros visible everywhere

    for (int t = 0; t < 512; ++t) {
        const half_t* hcur  = hbuf + (size_t)(t & 1) * 65536;
        half_t*       hnext = hbuf + (size_t)((t + 1) & 1) * 65536;

        f32x4 acc[2][4];
#pragma unroll
        for (int mb = 0; mb < 2; ++mb)
#pragma unroll
            for (int nb = 0; nb < 4; ++nb)
                acc[mb][nb] = (f32x4){0.f, 0.f, 0.f, 0.f};

        if (wave < 2) {
            // waves 0,1: A comes from x_t (fp32 -> fp16 on the fly, cached loads)
            const float* xp0 = x + ((size_t)t * 128 + r0 + l16) * 512 + wave * 256 + quad * 8;
            const float* xp1 = xp0 + (size_t)16 * 512;
#pragma unroll
            for (int kk = 0; kk < 8; ++kk) {
                float4 f0 = *(const float4*)(xp0 + kk * 32);
                float4 f1 = *(const float4*)(xp0 + kk * 32 + 4);
                float4 f2 = *(const float4*)(xp1 + kk * 32);
                float4 f3 = *(const float4*)(xp1 + kk * 32 + 4);
                half8 a0, a1;
                a0[0]=(half_t)f0.x; a0[1]=(half_t)f0.y; a0[2]=(half_t)f0.z; a0[3]=(half_t)f0.w;
                a0[4]=(half_t)f1.x; a0[5]=(half_t)f1.y; a0[6]=(half_t)f1.z; a0[7]=(half_t)f1.w;
                a1[0]=(half_t)f2.x; a1[1]=(half_t)f2.y; a1[2]=(half_t)f2.z; a1[3]=(half_t)f2.w;
                a1[4]=(half_t)f3.x; a1[5]=(half_t)f3.y; a1[6]=(half_t)f3.z; a1[7]=(half_t)f3.w;
#pragma unroll
                for (int nb = 0; nb < 4; ++nb) {
                    acc[0][nb] = __builtin_amdgcn_mfma_f32_16x16x32_f16(a0, wreg[kk][nb], acc[0][nb], 0, 0, 0);
                    acc[1][nb] = __builtin_amdgcn_mfma_f32_16x16x32_f16(a1, wreg[kk][nb], acc[1][nb], 0, 0, 0);
                }
            }
        } else {
            // waves 2,3: A comes from h (fp16 double buffer, coherent loads —
            // must bypass this XCD's stale L2 copy)
            const half_t* hp0 = hcur + (size_t)(r0 + l16) * 512 + (wave - 2) * 256 + quad * 8;
            const half_t* hp1 = hp0 + (size_t)16 * 512;
#pragma unroll
            for (int kk = 0; kk < 8; ++kk) {
                half8 a0 = coh_load16(hp0 + kk * 32);
                half8 a1 = coh_load16(hp1 + kk * 32);
#pragma unroll
                for (int nb = 0; nb < 4; ++nb) {
                    acc[0][nb] = __builtin_amdgcn_mfma_f32_16x16x32_f16(a0, wreg[kk][nb], acc[0][nb], 0, 0, 0);
                    acc[1][nb] = __builtin_amdgcn_mfma_f32_16x16x32_f16(a1, wreg[kk][nb], acc[1][nb], 0, 0, 0);
                }
            }
        }

        // C/D layout: col = lane&15, row = quad*4 + reg  (m89-verified)
#pragma unroll
        for (int mb = 0; mb < 2; ++mb)
#pragma unroll
            for (int nb = 0; nb < 4; ++nb) {
                f32x4 v = acc[mb][nb];
#pragma unroll
                for (int r = 0; r < 4; ++r)
                    P[wave][mb * 16 + quad * 4 + r][nb * 16 + l16] = v[r];
            }
        __syncthreads();

        // reduce 4 wave-partials + bias, activations, state update.
        // thread owns cells (b, 2jp) and (b, 2jp+1): adjacent h-cols ->
        // one packed u32 coherent hnext store + one float2 out store.
        {
            int b = tid >> 3, jp = tid & 7;
            float4 sA = {0.f,0.f,0.f,0.f}, sB = {0.f,0.f,0.f,0.f};
#pragma unroll
            for (int w = 0; w < 4; ++w) {
                float4 pA = *(const float4*)&P[w][b][8 * jp];
                float4 pB = *(const float4*)&P[w][b][8 * jp + 4];
                sA.x += pA.x; sA.y += pA.y; sA.z += pA.z; sA.w += pA.w;
                sB.x += pB.x; sB.y += pB.y; sB.z += pB.z; sB.w += pB.w;
            }
            const float* bp = biasp + 4 * (j0 + 2 * jp);
            float4 biA = *(const float4*)(bp);
            float4 biB = *(const float4*)(bp + 4);

            float gi0 = sA.x + biA.x, gf0 = sA.y + biA.y, gz0 = sA.z + biA.z, go0 = sA.w + biA.w;
            float gi1 = sB.x + biB.x, gf1 = sB.y + biB.y, gz1 = sB.z + biB.z, go1 = sB.w + biB.w;

            float ig0 = 1.f / (1.f + __expf(-gi0));
            float fg0 = 1.f / (1.f + __expf(-gf0));
            float zg0 = 1.f - 2.f / (__expf(2.f * gz0) + 1.f);
            float og0 = 1.f / (1.f + __expf(-go0));
            float ig1 = 1.f / (1.f + __expf(-gi1));
            float fg1 = 1.f / (1.f + __expf(-gf1));
            float zg1 = 1.f - 2.f / (__expf(2.f * gz1) + 1.f);
            float og1 = 1.f / (1.f + __expf(-go1));

            float cn0 = fg0 * c0 + ig0 * zg0;
            float cn1 = fg1 * c1 + ig1 * zg1;
            c0 = cn0; c1 = cn1;
            float hn0 = og0 * (1.f - 2.f / (__expf(2.f * cn0) + 1.f));
            float hn1 = og1 * (1.f - 2.f / (__expf(2.f * cn1) + 1.f));

            int bg = r0 + b, jg = j0 + 2 * jp;
            float2 o; o.x = hn0; o.y = hn1;
            *(float2*)(out + (size_t)t * 65536 + (size_t)bg * 512 + jg) = o;

            union { half_t h[2]; u32 u; } pk;
            pk.h[0] = (half_t)hn0; pk.h[1] = (half_t)hn1;
            coh_store4((u32*)(hnext + (size_t)bg * 512 + jg), pk.u);

            if (t == 511) {
                *(float2*)(out + (size_t)33554432 + (size_t)bg * 512 + jg) = o;          // hT
                float2 co; co.x = cn0; co.y = cn1;
                *(float2*)(out + (size_t)33554432 + 65536 + (size_t)bg * 512 + jg) = co; // cT
            }
        }

        grid_barrier(bar, t + 2);
    }
}

extern "C" void kernel_launch(void* const* d_in, const int* in_sizes, int n_in,
                              void* d_out, int out_size, void* d_ws, size_t ws_size,
                              hipStream_t stream)
{
    const float* x   = (const float*)d_in[0];
    // d_in[1] = time, unused by the base cell
    const float* Wih = (const float*)d_in[2];
    const float* Whh = (const float*)d_in[3];
    const float* bih = (const float*)d_in[4];
    const float* bhh = (const float*)d_in[5];
    unsigned char* ws = (unsigned char*)d_ws;
    float* out = (float*)d_out;

    prep_kernel<<<1025, 256, 0, stream>>>(Wih, Whh, bih, bhh, ws);
    lstm_persistent<<<NWG, 256, 0, stream>>>(x, out, ws);
}

// Round 3
// 2980.802 us; speedup vs baseline: 2.0899x; 1.5293x over previous
//
#include <hip/hip_runtime.h>

// LSTM T=512 B=128 I=H=512.  Persistent kernel, 128 WGs (each on its own CU),
// WG owns a [32 batch-rows x 16 h-cols] state slice for the whole sequence.
// Weights fp16 gate-interleaved in VGPRs. R3 design:
//  - Barrier = per-WG flag array (coherent plain stores, NO atomic RMW chain);
//    wave 0 polls all 128 flags (2 coherent loads/lane + __all).
//  - K re-split: every wave owns K=128 of x AND K=128 of h. The x-part GEMM
//    for step t+1 runs AFTER posting the step-t flag -> hidden under the
//    other WGs' tail latency. Only h-loads + h-MFMA + epilogue are on the
//    critical path after barrier release.
//  - Cross-XCD h/flag traffic: __hip_atomic_{store,load}(RELAXED, AGENT)
//    -> global ops with sc0 sc1 (coherence-point access, no cache flushes).
//    __syncthreads() drains vmcnt(0) per wave, so h-stores are visible
//    before the flag store that follows it.

typedef _Float16 half_t;
typedef _Float16 half8 __attribute__((ext_vector_type(8)));
typedef float f32x4 __attribute__((ext_vector_type(4)));
typedef unsigned long long u64;
typedef unsigned int u32;

#define NWG 128

// workspace layout (bytes)
#define WP_OFF   0u         // half [2048][1024]  gate-interleaved weights
#define BIAS_OFF 4194304u   // float [2048]       combined bias, interleaved
#define HBUF_OFF 4202496u   // half [2][128*512]  double-buffered h (fp16)
#define FLAG_OFF 4464640u   // int [128]          per-WG progress flags

__global__ void prep_kernel(const float* __restrict__ Wih,
                            const float* __restrict__ Whh,
                            const float* __restrict__ bih,
                            const float* __restrict__ bhh,
                            unsigned char* __restrict__ ws)
{
    half_t* Wp    = (half_t*)(ws + WP_OFF);
    float*  biasp = (float*)(ws + BIAS_OFF);
    int*    flags = (int*)(ws + FLAG_OFF);
    int bid = blockIdx.x, tid = threadIdx.x;
    if (bid < 1024) {
        // Wp[np][k], np = j*4+g  (j = h-col, g = gate i/f/g/o), K = [x | h]
        size_t e0 = ((size_t)bid * 256 + (size_t)tid) * 8;
        int np = (int)(e0 >> 10);
        int k  = (int)(e0 & 1023);
        int j = np >> 2, g = np & 3;
        int r = g * 512 + j;                      // row in original W_ih/W_hh
        const float* src = (k < 512) ? (Wih + (size_t)r * 512 + k)
                                     : (Whh + (size_t)r * 512 + (k - 512));
        float4 f0 = *(const float4*)(src);
        float4 f1 = *(const float4*)(src + 4);
        half8 h;
        h[0]=(half_t)f0.x; h[1]=(half_t)f0.y; h[2]=(half_t)f0.z; h[3]=(half_t)f0.w;
        h[4]=(half_t)f1.x; h[5]=(half_t)f1.y; h[6]=(half_t)f1.z; h[7]=(half_t)f1.w;
        *(half8*)(Wp + e0) = h;
    } else {
        for (int n = tid; n < 2048; n += 256) {
            int j = n >> 2, g = n & 3;
            int r = g * 512 + j;
            biasp[n] = bih[r] + bhh[r];
        }
        if (tid < NWG) flags[tid] = 0;
    }
}

// coherent (agent-scope, L2-bypassing) helpers — no cache maintenance
__device__ __forceinline__ half8 coh_load16(const half_t* p) {
    union { u64 q[2]; half8 h; } u;
    u.q[0] = __hip_atomic_load((const u64*)p,     __ATOMIC_RELAXED, __HIP_MEMORY_SCOPE_AGENT);
    u.q[1] = __hip_atomic_load((const u64*)p + 1, __ATOMIC_RELAXED, __HIP_MEMORY_SCOPE_AGENT);
    return u.h;
}
__device__ __forceinline__ void coh_store4(u32* p, u32 v) {
    __hip_atomic_store(p, v, __ATOMIC_RELAXED, __HIP_MEMORY_SCOPE_AGENT);
}
__device__ __forceinline__ int coh_load_i(const int* p) {
    return __hip_atomic_load(p, __ATOMIC_RELAXED, __HIP_MEMORY_SCOPE_AGENT);
}

__global__ __launch_bounds__(256, 1) void lstm_persistent(
    const float* __restrict__ x, float* __restrict__ out,
    unsigned char* __restrict__ ws)
{
    const half_t* Wp    = (const half_t*)(ws + WP_OFF);
    const float*  biasp = (const float*)(ws + BIAS_OFF);
    half_t*       hbuf  = (half_t*)(ws + HBUF_OFF);
    int*          flags = (int*)(ws + FLAG_OFF);

    const int tid  = threadIdx.x;
    const int wave = tid >> 6, lane = tid & 63;
    const int quad = lane >> 4, l16 = lane & 15;
    const int bid  = blockIdx.x;
    const int rowg = bid & 3, colg = bid >> 2;
    const int r0 = rowg * 32;     // batch rows [r0, r0+32)
    const int j0 = colg * 16;     // h-cols    [j0, j0+16)

    // ---- stationary W fragments.  Wave w owns x-K [128w,128w+128) and
    // h-K [512+128w, 512+128w+128), for all 64 gate cols of this WG.
    // lane holds W[np = 4*j0 + nb*16 + l16][k = kbase + kk*32 + quad*8 + 0..7]
    half8 wx[4][4], wh[4][4];
    {
        const half_t* wb = Wp + ((size_t)(4 * j0 + l16)) * 1024 + 128 * wave + quad * 8;
#pragma unroll
        for (int kk = 0; kk < 4; ++kk)
#pragma unroll
            for (int nb = 0; nb < 4; ++nb) {
                wx[kk][nb] = *(const half8*)(wb + (size_t)nb * 16 * 1024 + kk * 32);
                wh[kk][nb] = *(const half8*)(wb + (size_t)nb * 16 * 1024 + 512 + kk * 32);
            }
    }

    // zero this WG's slice of h buffer 0 (coherent: readers bypass L2)
    {
        int b = tid >> 3, jp = tid & 7;
        coh_store4((u32*)(hbuf + (size_t)(r0 + b) * 512 + j0 + 2 * jp), 0u);
    }
    __syncthreads();                       // drain zero-stores (vmcnt(0))
    if (tid == 0) coh_store4((u32*)&flags[bid], 1u);

    __shared__ float P[4][32][68];   // per-wave partial gates [wave][row][gatecol]

    float c0 = 0.f, c1 = 0.f;        // cell state: cells (b,2jp),(b,2jp+1)
    f32x4 acc[2][4];

    // x-part GEMM for step tt into acc (acc must be pre-zeroed by caller side)
    auto x_phase = [&](int tt) {
        const float* xp0 = x + ((size_t)tt * 128 + r0 + l16) * 512 + 128 * wave + quad * 8;
        const float* xp1 = xp0 + (size_t)16 * 512;
#pragma unroll
        for (int kk = 0; kk < 4; ++kk) {
            float4 f0 = *(const float4*)(xp0 + kk * 32);
            float4 f1 = *(const float4*)(xp0 + kk * 32 + 4);
            float4 f2 = *(const float4*)(xp1 + kk * 32);
            float4 f3 = *(const float4*)(xp1 + kk * 32 + 4);
            half8 a0, a1;
            a0[0]=(half_t)f0.x; a0[1]=(half_t)f0.y; a0[2]=(half_t)f0.z; a0[3]=(half_t)f0.w;
            a0[4]=(half_t)f1.x; a0[5]=(half_t)f1.y; a0[6]=(half_t)f1.z; a0[7]=(half_t)f1.w;
            a1[0]=(half_t)f2.x; a1[1]=(half_t)f2.y; a1[2]=(half_t)f2.z; a1[3]=(half_t)f2.w;
            a1[4]=(half_t)f3.x; a1[5]=(half_t)f3.y; a1[6]=(half_t)f3.z; a1[7]=(half_t)f3.w;
#pragma unroll
            for (int nb = 0; nb < 4; ++nb) {
                acc[0][nb] = __builtin_amdgcn_mfma_f32_16x16x32_f16(a0, wx[kk][nb], acc[0][nb], 0, 0, 0);
                acc[1][nb] = __builtin_amdgcn_mfma_f32_16x16x32_f16(a1, wx[kk][nb], acc[1][nb], 0, 0, 0);
            }
        }
    };

#pragma unroll
    for (int mb = 0; mb < 2; ++mb)
#pragma unroll
        for (int nb = 0; nb < 4; ++nb)
            acc[mb][nb] = (f32x4){0.f, 0.f, 0.f, 0.f};
    x_phase(0);                      // hidden behind other WGs' startup

    for (int t = 0; t < 512; ++t) {
        // ---- wait for all WGs to have published h_t (gen t+1) ----
        if (wave == 0) {
            int gen = t + 1;
            for (;;) {
                int f0 = coh_load_i(&flags[lane]);
                int f1 = coh_load_i(&flags[lane + 64]);
                if (__all((f0 >= gen) && (f1 >= gen))) break;
                __builtin_amdgcn_s_sleep(1);
            }
        }
        __syncthreads();

        const half_t* hcur  = hbuf + (size_t)(t & 1) * 65536;
        half_t*       hnext = hbuf + (size_t)((t + 1) & 1) * 65536;

        // ---- h-part: coherent loads (bypass stale L2), then MFMA ----
        {
            const half_t* hp0 = hcur + (size_t)(r0 + l16) * 512 + 128 * wave + quad * 8;
            const half_t* hp1 = hp0 + (size_t)16 * 512;
            half8 a0[4], a1[4];
#pragma unroll
            for (int kk = 0; kk < 4; ++kk) {
                a0[kk] = coh_load16(hp0 + kk * 32);
                a1[kk] = coh_load16(hp1 + kk * 32);
            }
#pragma unroll
            for (int kk = 0; kk < 4; ++kk)
#pragma unroll
                for (int nb = 0; nb < 4; ++nb) {
                    acc[0][nb] = __builtin_amdgcn_mfma_f32_16x16x32_f16(a0[kk], wh[kk][nb], acc[0][nb], 0, 0, 0);
                    acc[1][nb] = __builtin_amdgcn_mfma_f32_16x16x32_f16(a1[kk], wh[kk][nb], acc[1][nb], 0, 0, 0);
                }
        }

        // C/D layout: col = lane&15, row = quad*4 + reg  (m89-verified)
#pragma unroll
        for (int mb = 0; mb < 2; ++mb)
#pragma unroll
            for (int nb = 0; nb < 4; ++nb) {
                f32x4 v = acc[mb][nb];
#pragma unroll
                for (int r = 0; r < 4; ++r)
                    P[wave][mb * 16 + quad * 4 + r][nb * 16 + l16] = v[r];
            }
        __syncthreads();

        // ---- reduce 4 wave-partials + bias, activations, state update ----
        // thread owns cells (b, 2jp),(b, 2jp+1): one packed u32 coherent
        // hnext store + one float2 out store.
        {
            int b = tid >> 3, jp = tid & 7;
            float4 sA = {0.f,0.f,0.f,0.f}, sB = {0.f,0.f,0.f,0.f};
#pragma unroll
            for (int w = 0; w < 4; ++w) {
                float4 pA = *(const float4*)&P[w][b][8 * jp];
                float4 pB = *(const float4*)&P[w][b][8 * jp + 4];
                sA.x += pA.x; sA.y += pA.y; sA.z += pA.z; sA.w += pA.w;
                sB.x += pB.x; sB.y += pB.y; sB.z += pB.z; sB.w += pB.w;
            }
            const float* bp = biasp + 4 * (j0 + 2 * jp);
            float4 biA = *(const float4*)(bp);
            float4 biB = *(const float4*)(bp + 4);

            float gi0 = sA.x + biA.x, gf0 = sA.y + biA.y, gz0 = sA.z + biA.z, go0 = sA.w + biA.w;
            float gi1 = sB.x + biB.x, gf1 = sB.y + biB.y, gz1 = sB.z + biB.z, go1 = sB.w + biB.w;

            float ig0 = 1.f / (1.f + __expf(-gi0));
            float fg0 = 1.f / (1.f + __expf(-gf0));
            float zg0 = 1.f - 2.f / (__expf(2.f * gz0) + 1.f);
            float og0 = 1.f / (1.f + __expf(-go0));
            float ig1 = 1.f / (1.f + __expf(-gi1));
            float fg1 = 1.f / (1.f + __expf(-gf1));
            float zg1 = 1.f - 2.f / (__expf(2.f * gz1) + 1.f);
            float og1 = 1.f / (1.f + __expf(-go1));

            float cn0 = fg0 * c0 + ig0 * zg0;
            float cn1 = fg1 * c1 + ig1 * zg1;
            c0 = cn0; c1 = cn1;
            float hn0 = og0 * (1.f - 2.f / (__expf(2.f * cn0) + 1.f));
            float hn1 = og1 * (1.f - 2.f / (__expf(2.f * cn1) + 1.f));

            int bg = r0 + b, jg = j0 + 2 * jp;
            float2 o; o.x = hn0; o.y = hn1;
            *(float2*)(out + (size_t)t * 65536 + (size_t)bg * 512 + jg) = o;

            union { half_t h[2]; u32 u; } pk;
            pk.h[0] = (half_t)hn0; pk.h[1] = (half_t)hn1;
            coh_store4((u32*)(hnext + (size_t)bg * 512 + jg), pk.u);

            if (t == 511) {
                *(float2*)(out + (size_t)33554432 + (size_t)bg * 512 + jg) = o;          // hT
                float2 co; co.x = cn0; co.y = cn1;
                *(float2*)(out + (size_t)33554432 + 65536 + (size_t)bg * 512 + jg) = co; // cT
            }
        }
        __syncthreads();             // drain h/out stores of ALL waves (vmcnt 0)
        if (tid == 0) coh_store4((u32*)&flags[bid], (u32)(t + 2));

        // ---- x-part for step t+1: off the critical path, hides under the
        // tail of other WGs finishing step t ----
        if (t < 511) {
#pragma unroll
            for (int mb = 0; mb < 2; ++mb)
#pragma unroll
                for (int nb = 0; nb < 4; ++nb)
                    acc[mb][nb] = (f32x4){0.f, 0.f, 0.f, 0.f};
            x_phase(t + 1);
        }
    }
}

extern "C" void kernel_launch(void* const* d_in, const int* in_sizes, int n_in,
                              void* d_out, int out_size, void* d_ws, size_t ws_size,
                              hipStream_t stream)
{
    const float* x   = (const float*)d_in[0];
    // d_in[1] = time, unused by the base cell
    const float* Wih = (const float*)d_in[2];
    const float* Whh = (const float*)d_in[3];
    const float* bih = (const float*)d_in[4];
    const float* bhh = (const float*)d_in[5];
    unsigned char* ws = (unsigned char*)d_ws;
    float* out = (float*)d_out;

    prep_kernel<<<1025, 256, 0, stream>>>(Wih, Whh, bih, bhh, ws);
    lstm_persistent<<<NWG, 256, 0, stream>>>(x, out, ws);
}